// Round 11
// baseline (772.977 us; speedup 1.0000x reference)
//
#include <hip/hip_runtime.h>
#include <hip/hip_bf16.h>

// MLA transformer block on MI355X. Round 11: fix k_gemm4 staging to honor
// global_load_lds's wave-uniform-dest + lane*16 semantics (m104/m173):
// each instruction fills one contiguous 1024B LDS block; per-lane GLOBAL
// source re-derived from granule index. Ring-4 schedule unchanged.

typedef short bf16x8 __attribute__((ext_vector_type(8)));
typedef float f32x4 __attribute__((ext_vector_type(4)));
typedef unsigned short u16;

#define BM 128
#define BN 128
#define BK 32

__device__ __forceinline__ u16 f2bf(float f) {
  unsigned int u = __builtin_bit_cast(unsigned int, f);
  u += 0x7FFFu + ((u >> 16) & 1u);
  return (u16)(u >> 16);
}

__device__ __forceinline__ void gload_lds16(const void* g, void* l) {
  __builtin_amdgcn_global_load_lds(
      (const __attribute__((address_space(1))) unsigned int*)(uintptr_t)g,
      (__attribute__((address_space(3))) unsigned int*)(unsigned int)(uintptr_t)l,
      16, 0, 0);
}

// ---------------- transpose + f32->bf16 : out[N][K] = (bf16) in[K][N] ------
__global__ __launch_bounds__(256) void k_transpose_bf16(
    const float* __restrict__ in, u16* __restrict__ out, int K, int N) {
  __shared__ float tile[32][33];
  int k0 = blockIdx.x * 32, n0 = blockIdx.y * 32;
  int tx = threadIdx.x & 31, ty = threadIdx.x >> 5;
#pragma unroll
  for (int i = 0; i < 4; ++i) {
    int k = k0 + ty + i * 8, n = n0 + tx;
    tile[ty + i * 8][tx] = (k < K && n < N) ? in[(size_t)k * N + n] : 0.f;
  }
  __syncthreads();
#pragma unroll
  for (int i = 0; i < 4; ++i) {
    int n = n0 + ty + i * 8, k = k0 + tx;
    if (n < N && k < K) out[(size_t)n * K + k] = f2bf(tile[tx][ty + i * 8]);
  }
}

// ---------------- V transpose per (b,h): vb[m][h*128+d] -> vbT[bh][d][s] ----
__global__ __launch_bounds__(256) void k_transpose_v(
    const u16* __restrict__ vb, u16* __restrict__ vbT) {
  __shared__ u16 tile[32][34];
  int bh = blockIdx.z, b = bh >> 4, h = bh & 15;
  int s0 = blockIdx.x * 32, d0 = blockIdx.y * 32;
  int tx = threadIdx.x & 31, ty = threadIdx.x >> 5;
#pragma unroll
  for (int i = 0; i < 4; ++i)
    tile[ty + i * 8][tx] =
        vb[((size_t)b * 2048 + s0 + ty + i * 8) * 2048 + h * 128 + d0 + tx];
  __syncthreads();
#pragma unroll
  for (int i = 0; i < 4; ++i)
    vbT[((size_t)bh * 128 + d0 + ty + i * 8) * 2048 + s0 + tx] = tile[tx][ty + i * 8];
}

// ---------------- RoPE tables: cos/sin[s][i], i<32 -------------------------
__global__ void k_rope_table(float* __restrict__ cosT, float* __restrict__ sinT) {
  int idx = blockIdx.x * 256 + threadIdx.x;
  if (idx >= 2048 * 32) return;
  int s = idx >> 5, i = idx & 31;
  float inv = exp2f(-(float)i * 0.41524101186092037f); // log2(10000)/32
  float a = (float)s * inv;
  cosT[idx] = cosf(a);
  sinT[idx] = sinf(a);
}

// ---------------- LayerNorm row=2048, out bf16 -----------------------------
__global__ __launch_bounds__(256) void k_ln(const float* __restrict__ x,
                                            const float* __restrict__ w,
                                            const float* __restrict__ b,
                                            u16* __restrict__ out) {
  const int row = blockIdx.x, tid = threadIdx.x;
  const float* xr = x + (size_t)row * 2048;
  float xv[8];
  *(float4*)&xv[0] = ((const float4*)xr)[tid * 2];
  *(float4*)&xv[4] = ((const float4*)xr)[tid * 2 + 1];
  float s = 0.f, ss = 0.f;
#pragma unroll
  for (int j = 0; j < 8; ++j) { s += xv[j]; ss += xv[j] * xv[j]; }
#pragma unroll
  for (int m_ = 32; m_; m_ >>= 1) { s += __shfl_xor(s, m_); ss += __shfl_xor(ss, m_); }
  __shared__ float red[8];
  const int wv = tid >> 6;
  if ((tid & 63) == 0) { red[wv] = s; red[wv + 4] = ss; }
  __syncthreads();
  s = red[0] + red[1] + red[2] + red[3];
  ss = red[4] + red[5] + red[6] + red[7];
  const float mean = s * (1.f / 2048.f);
  const float rs = rsqrtf(ss * (1.f / 2048.f) - mean * mean + 1e-5f);
  float wv8[8], bv8[8];
  *(float4*)&wv8[0] = ((const float4*)w)[tid * 2];
  *(float4*)&wv8[4] = ((const float4*)w)[tid * 2 + 1];
  *(float4*)&bv8[0] = ((const float4*)b)[tid * 2];
  *(float4*)&bv8[4] = ((const float4*)b)[tid * 2 + 1];
  u16 t[8] __attribute__((aligned(16)));
#pragma unroll
  for (int j = 0; j < 8; ++j) t[j] = f2bf((xv[j] - mean) * rs * wv8[j] + bv8[j]);
  *(int4*)&out[(size_t)row * 2048 + tid * 8] = *(int4*)t;
}

// ---------------- RoPE: qr f32 -> qall bf16 (cols 128..191) ----------------
__global__ void k_rope_q(const float* __restrict__ qr, const float* __restrict__ cosT,
                         const float* __restrict__ sinT, u16* __restrict__ qall) {
  int idx = blockIdx.x * 256 + threadIdx.x; // 4096*16*32
  if (idx >= 4096 * 16 * 32) return;
  int i = idx & 31, rest = idx >> 5;
  int h = rest & 15, m = rest >> 4;
  int s = m & 2047, b = m >> 11;
  float c = cosT[s * 32 + i], sn = sinT[s * 32 + i];
  const float* p = qr + (size_t)m * 1024 + h * 64 + i;
  float x0 = p[0], x1 = p[32];
  u16* q = qall + ((size_t)(b * 16 + h) * 2048 + s) * 192 + 128 + i;
  q[0] = f2bf(x0 * c - x1 * sn);
  q[32] = f2bf(x1 * c + x0 * sn);
}

// ---------------- RoPE: kr f32 -> krb_bf bf16 + nkv f32 --------------------
__global__ void k_rope_k(const float* __restrict__ kr, const float* __restrict__ cosT,
                         const float* __restrict__ sinT, float* __restrict__ nkv,
                         u16* __restrict__ krb_bf) {
  int idx = blockIdx.x * 256 + threadIdx.x; // 4096*32
  if (idx >= 4096 * 32) return;
  int i = idx & 31, m = idx >> 5;
  int s = m & 2047;
  float c = cosT[s * 32 + i], sn = sinT[s * 32 + i];
  const float* p = kr + (size_t)m * 64 + i;
  float x0 = p[0], x1 = p[32];
  float y0 = x0 * c - x1 * sn;
  float y1 = x1 * c + x0 * sn;
  nkv[(size_t)m * 576 + 512 + i] = y0;
  nkv[(size_t)m * 576 + 544 + i] = y1;
  krb_bf[(size_t)m * 64 + i] = f2bf(y0);
  krb_bf[(size_t)m * 64 + 32 + i] = f2bf(y1);
}

enum { EP_Q = 0, EP_DKV = 1, EP_KV = 2, EP_RES = 3, EP_GELU = 4 };

// ---------------- small GEMM (dkv only): m97 128x128xBK32 ------------------
template <int EP>
__global__ __launch_bounds__(256) void k_gemm(
    const u16* __restrict__ A, const u16* __restrict__ Bt,
    const float* __restrict__ bias, int K, int Nreal,
    void* out0_, void* out1_, void* out2_, const float* __restrict__ res) {
  __shared__ u16 As[BM * BK];
  __shared__ u16 Bs[BN * BK];
  const int tid = threadIdx.x;
  const int w = tid >> 6, lane = tid & 63;
  const int bm = blockIdx.y * BM, bn = blockIdx.x * BN;
  const int wr = (w >> 1) * 64, wc = (w & 1) * 64;

  const u16* Ag = A + (size_t)(bm + w * 32 + (lane >> 2)) * K + (lane & 3) * 8;
  const u16* Bg = Bt + (size_t)(bn + w * 32 + (lane >> 2)) * K + (lane & 3) * 8;
  char* lA = (char*)As + w * 2048;
  char* lB = (char*)Bs + w * 2048;

  f32x4 acc[4][4] = {};
  for (int k0 = 0; k0 < K; k0 += BK) {
    __syncthreads();
    gload_lds16(Ag, lA);
    gload_lds16(Ag + 16 * K, lA + 1024);
    gload_lds16(Bg, lB);
    gload_lds16(Bg + 16 * K, lB + 1024);
    Ag += BK; Bg += BK;
    __syncthreads();
    const int ka = (lane >> 4) * 8;
    const int lc = lane & 15;
    bf16x8 av[4], bv[4];
#pragma unroll
    for (int i = 0; i < 4; ++i) av[i] = *(const bf16x8*)&As[(wr + i * 16 + lc) * BK + ka];
#pragma unroll
    for (int j = 0; j < 4; ++j) bv[j] = *(const bf16x8*)&Bs[(wc + j * 16 + lc) * BK + ka];
#pragma unroll
    for (int i = 0; i < 4; ++i)
#pragma unroll
      for (int j = 0; j < 4; ++j)
        acc[i][j] = __builtin_amdgcn_mfma_f32_16x16x32_bf16(av[i], bv[j], acc[i][j], 0, 0, 0);
  }

  const int lr = (lane >> 4) * 4, lc = lane & 15;
#pragma unroll
  for (int i = 0; i < 4; ++i) {
#pragma unroll
    for (int j = 0; j < 4; ++j) {
      int col = bn + wc + j * 16 + lc;
      if (col >= Nreal) continue;
      float bb = bias ? bias[col] : 0.f;
#pragma unroll
      for (int r = 0; r < 4; ++r) {
        int row = bm + wr + i * 16 + lr + r;
        float c = acc[i][j][r] + bb;
        if constexpr (EP == EP_DKV) {
          u16* ckv = (u16*)out0_; float* nkv = (float*)out1_; float* kr = (float*)out2_;
          if (col < 512) { ckv[(size_t)row * 512 + col] = f2bf(c); nkv[(size_t)row * 576 + col] = c; }
          else kr[(size_t)row * 64 + (col - 512)] = c;
        }
      }
    }
  }
}

// ---------------- big GEMM v2: 128x256, BK=64, counted vmcnt (o, w2) -------
template <int EP>
__global__ __launch_bounds__(512, 2) void k_gemm2(
    const u16* __restrict__ A, const u16* __restrict__ Bt,
    const float* __restrict__ bias, int K, int gx, int Nreal,
    void* out0_, void* out1_, const float* __restrict__ res) {
  __shared__ u16 As[2][128 * 64];
  __shared__ u16 Bs[2][256 * 64];
  const int tid = threadIdx.x;
  const int w = tid >> 6, lane = tid & 63;
  const int q8 = (int)gridDim.x >> 3;
  const int u = ((int)blockIdx.x & 7) * q8 + ((int)blockIdx.x >> 3);
  const int bn = (u % gx) * 256, bm = (u / gx) * 128;
  const int wr = (w >> 2) * 64, wc = (w & 3) * 64;
  const int lc = lane & 15, hi = lane >> 4;

  const int rowid = tid >> 3;
  const int gsw = (tid & 7) ^ (rowid & 7);
  const u16* Ag = A + (size_t)(bm + rowid) * K + gsw * 8;
  const u16* Bg = Bt + (size_t)(bn + rowid) * K + gsw * 8;

  auto stage = [&](int buf, int k0) {
    char* lA = (char*)&As[buf][0] + tid * 16;
    char* lB = (char*)&Bs[buf][0] + tid * 16;
#pragma unroll
    for (int i = 0; i < 2; ++i)
      gload_lds16(Ag + (size_t)i * 64 * K + k0, lA + i * 8192);
#pragma unroll
    for (int i = 0; i < 4; ++i)
      gload_lds16(Bg + (size_t)i * 64 * K + k0, lB + i * 8192);
  };

  f32x4 acc[4][4] = {};
  const int NT = K >> 6;
  stage(0, 0);
  for (int t = 0; t < NT; ++t) {
    if (t + 1 < NT) {
      stage((t + 1) & 1, (t + 1) * 64);
      asm volatile("s_waitcnt vmcnt(6)" ::: "memory");
    } else {
      asm volatile("s_waitcnt vmcnt(0)" ::: "memory");
    }
    __builtin_amdgcn_s_barrier();
    __builtin_amdgcn_sched_barrier(0);
    const char* AsB = (const char*)&As[t & 1][0];
    const char* BsB = (const char*)&Bs[t & 1][0];
#pragma unroll
    for (int ks = 0; ks < 2; ++ks) {
      bf16x8 av[4], bv[4];
#pragma unroll
      for (int mi = 0; mi < 4; ++mi) {
        int row = wr + mi * 16 + lc;
        av[mi] = *(const bf16x8*)(AsB + row * 128 + (((ks * 4 + hi) ^ (row & 7)) << 4));
      }
#pragma unroll
      for (int ni = 0; ni < 4; ++ni) {
        int row = wc + ni * 16 + lc;
        bv[ni] = *(const bf16x8*)(BsB + row * 128 + (((ks * 4 + hi) ^ (row & 7)) << 4));
      }
#pragma unroll
      for (int mi = 0; mi < 4; ++mi)
#pragma unroll
        for (int ni = 0; ni < 4; ++ni)
          acc[mi][ni] = __builtin_amdgcn_mfma_f32_16x16x32_bf16(av[mi], bv[ni], acc[mi][ni], 0, 0, 0);
    }
    asm volatile("s_waitcnt lgkmcnt(0)" ::: "memory");
    __builtin_amdgcn_s_barrier();
  }

#pragma unroll
  for (int mi = 0; mi < 4; ++mi) {
#pragma unroll
    for (int ni = 0; ni < 4; ++ni) {
      int col = bn + wc + ni * 16 + lc;
      float bb = bias[col];
#pragma unroll
      for (int r = 0; r < 4; ++r) {
        int row = bm + wr + mi * 16 + hi * 4 + r;
        int b = row >> 11, s = row & 2047;
        float c = acc[mi][ni][r] + bb;
        if constexpr (EP == EP_Q) {
          u16* qall = (u16*)out0_; float* qr = (float*)out1_;
          int hh = col / 192, d = col - hh * 192;
          if (d < 128) qall[((size_t)(b * 16 + hh) * 2048 + s) * 192 + d] = f2bf(c);
          else qr[(size_t)row * 1024 + hh * 64 + (d - 128)] = c;
        } else if constexpr (EP == EP_KV) {
          u16* knb2h = (u16*)out0_; u16* vv = (u16*)out1_;
          int hh = col >> 8, d = col & 255;
          if (d < 128) knb2h[((size_t)(b * 16 + hh) * 2048 + s) * 128 + d] = f2bf(c);
          else vv[(size_t)row * 2048 + hh * 128 + (d - 128)] = f2bf(c);
        } else if constexpr (EP == EP_RES) {
          float* out = (float*)out0_;
          out[(size_t)row * Nreal + col] = res[(size_t)row * Nreal + col] + c;
        } else { // EP_GELU
          u16* g = (u16*)out0_;
          float gl = 0.5f * c * (1.f + erff(c * 0.70710678118f));
          g[(size_t)row * Nreal + col] = f2bf(gl);
        }
      }
    }
  }
}

// ---------------- big GEMM v4: 256x256, BK=32, 4-deep buffer ring ----------
// 8 waves (2Mx4N), per-wave 128x64, acc[8][4]. LDS: As/Bs[4][256*32] (128KB).
// STAGING (fixed): each gload_lds16 fills one contiguous 1024B LDS block
// (wave-uniform dest; HW adds lane*16). Per-lane global source from granule
// G=(w*2+i)*64+lane -> row=G>>2, colgranule=G&3 (LDS byte off == G*16).
// Step s: vmcnt(8) [tile s landed; s+1,s+2 in flight] -> barrier -> stage
// tile s+3 into buf (s-1)&3 -> ds_read -> lgkmcnt(0) -> 32 MFMA (setprio).
template <int EP>
__global__ __launch_bounds__(512, 1) void k_gemm4(
    const u16* __restrict__ A, const u16* __restrict__ Bt,
    const float* __restrict__ bias, int K, int gx, int Nreal,
    void* out0_, void* out1_, const float* __restrict__ res) {
  __shared__ u16 As[4][256 * 32];
  __shared__ u16 Bs[4][256 * 32];
  const int tid = threadIdx.x;
  const int w = tid >> 6, lane = tid & 63;
  const int q8 = (int)gridDim.x >> 3;
  const int u = ((int)blockIdx.x & 7) * q8 + ((int)blockIdx.x >> 3);
  const int bn = (u % gx) * 256, bm = (u / gx) * 256;
  const int wm = (w >> 2) * 128, wn = (w & 3) * 64;
  const int lc = lane & 15, hi = lane >> 4;

  const u16* Agb = A + (size_t)bm * K;
  const u16* Bgb = Bt + (size_t)bn * K;
  // per-lane global source offsets for the 2 blocks this wave stages
  size_t srcoff[2];
#pragma unroll
  for (int i = 0; i < 2; ++i) {
    int G = (w * 2 + i) * 64 + lane;     // granule 0..1023
    int row = G >> 2, g = G & 3;
    srcoff[i] = (size_t)row * K + g * 8;
  }

  auto stage = [&](int buf, int k0) {
#pragma unroll
    for (int i = 0; i < 2; ++i) {
      gload_lds16(Agb + srcoff[i] + k0, (char*)&As[buf][0] + (w * 2 + i) * 1024);
      gload_lds16(Bgb + srcoff[i] + k0, (char*)&Bs[buf][0] + (w * 2 + i) * 1024);
    }
  };

  f32x4 acc[8][4] = {};
  const int NS = K >> 5;
  stage(0, 0);
  stage(1, 32);
  stage(2, 64);

  for (int s = 0; s < NS; ++s) {
    if (s + 2 < NS)      { asm volatile("s_waitcnt vmcnt(8)" ::: "memory"); }
    else if (s + 1 < NS) { asm volatile("s_waitcnt vmcnt(4)" ::: "memory"); }
    else                 { asm volatile("s_waitcnt vmcnt(0)" ::: "memory"); }
    __builtin_amdgcn_s_barrier();     // tile s visible; step s-1 reads done
    __builtin_amdgcn_sched_barrier(0);
    if (s + 3 < NS) stage((s + 3) & 3, (s + 3) * 32);
    __builtin_amdgcn_sched_barrier(0);

    const char* AsB = (const char*)&As[s & 3][0];
    const char* BsB = (const char*)&Bs[s & 3][0];
    bf16x8 av[8], bv[4];
#pragma unroll
    for (int mi = 0; mi < 8; ++mi)
      av[mi] = *(const bf16x8*)(AsB + (wm + mi * 16 + lc) * 64 + hi * 16);
#pragma unroll
    for (int ni = 0; ni < 4; ++ni)
      bv[ni] = *(const bf16x8*)(BsB + (wn + ni * 16 + lc) * 64 + hi * 16);
    asm volatile("s_waitcnt lgkmcnt(0)" ::: "memory");
    __builtin_amdgcn_sched_barrier(0);
    __builtin_amdgcn_s_setprio(1);
#pragma unroll
    for (int mi = 0; mi < 8; ++mi)
#pragma unroll
      for (int ni = 0; ni < 4; ++ni)
        acc[mi][ni] = __builtin_amdgcn_mfma_f32_16x16x32_bf16(av[mi], bv[ni], acc[mi][ni], 0, 0, 0);
    __builtin_amdgcn_s_setprio(0);
  }

#pragma unroll
  for (int mi = 0; mi < 8; ++mi) {
#pragma unroll
    for (int ni = 0; ni < 4; ++ni) {
      int col = bn + wn + ni * 16 + lc;
      float bb = bias[col];
#pragma unroll
      for (int r = 0; r < 4; ++r) {
        int row = bm + wm + mi * 16 + hi * 4 + r;
        int b = row >> 11, s = row & 2047;
        float c = acc[mi][ni][r] + bb;
        if constexpr (EP == EP_Q) {
          u16* qall = (u16*)out0_; float* qr = (float*)out1_;
          int hh = col / 192, d = col - hh * 192;
          if (d < 128) qall[((size_t)(b * 16 + hh) * 2048 + s) * 192 + d] = f2bf(c);
          else qr[(size_t)row * 1024 + hh * 64 + (d - 128)] = c;
        } else if constexpr (EP == EP_KV) {
          u16* knb2h = (u16*)out0_; u16* vv = (u16*)out1_;
          int hh = col >> 8, d = col & 255;
          if (d < 128) knb2h[((size_t)(b * 16 + hh) * 2048 + s) * 128 + d] = f2bf(c);
          else vv[(size_t)row * 2048 + hh * 128 + (d - 128)] = f2bf(c);
        } else if constexpr (EP == EP_RES) {
          float* out = (float*)out0_;
          out[(size_t)row * Nreal + col] = res[(size_t)row * Nreal + col] + c;
        } else { // EP_GELU
          u16* g = (u16*)out0_;
          float gl = 0.5f * c * (1.f + erff(c * 0.70710678118f));
          g[(size_t)row * Nreal + col] = f2bf(gl);
        }
      }
    }
  }
}

// ---------------- Flash attention: gload_lds staging, K dbuf, V single -----
__global__ __launch_bounds__(256) void k_attn(
    const u16* __restrict__ qall, const u16* __restrict__ knb2h,
    const u16* __restrict__ krb_bf, const u16* __restrict__ vbT,
    u16* __restrict__ o) {
  __shared__ u16 Ks[2][64 * 192];
  __shared__ u16 Vt[128 * 64];
  __shared__ u16 Ps[64 * 72];
  const int lin = blockIdx.x;
  const int qt = 31 - (lin >> 5);
  const int bh = (((lin >> 3) & 3) << 3) | (lin & 7);
  const int b = bh >> 4;
  const int tid = threadIdx.x, w = tid >> 6, lane = tid & 63;
  const float sc2 = 0.07216878365f * 1.4426950408f;
  const int lr = (lane >> 4) * 4, lc = lane & 15, ka = (lane >> 4) * 8;

  bf16x8 qf[6];
  {
    const u16* qrow = qall + ((size_t)bh * 2048 + qt * 64 + w * 16 + lc) * 192;
#pragma unroll
    for (int ks = 0; ks < 6; ++ks) qf[ks] = *(const bf16x8*)&qrow[ks * 32 + ka];
  }

  const char* kp[6];
  int kstr[6];
  {
    const char* knB = (const char*)(knb2h + (size_t)bh * 2048 * 128);
    const char* krB = (const char*)(krb_bf + (size_t)b * 2048 * 64);
#pragma unroll
    for (int i = 0; i < 6; ++i) {
      int G = (i * 4 + w) * 64 + lane;
      int row = G / 24, g = G - row * 24;
      int gs = g ^ (row & 7);
      if (gs < 16) { kp[i] = knB + row * 256 + gs * 16; kstr[i] = 16384; }
      else         { kp[i] = krB + row * 128 + (gs - 16) * 16; kstr[i] = 8192; }
    }
  }
  const char* vp[4];
  {
    const char* vB = (const char*)(vbT + (size_t)bh * 128 * 2048);
#pragma unroll
    for (int i = 0; i < 4; ++i) {
      int G = (i * 4 + w) * 64 + lane;
      int d = G >> 3, g = G & 7;
      vp[i] = vB + d * 4096 + ((g ^ (d & 7)) << 4);
    }
  }

#pragma unroll
  for (int i = 0; i < 6; ++i)
    gload_lds16(kp[i], (char*)&Ks[0][0] + (i * 4 + w) * 1024);
#pragma unroll
  for (int i = 0; i < 6; ++i) kp[i] += kstr[i];
  asm volatile("s_waitcnt vmcnt(0)" ::: "memory");
  __builtin_amdgcn_s_barrier();
  __builtin_amdgcn_sched_barrier(0);

  float m2[4] = {-1e30f, -1e30f, -1e30f, -1e30f};
  float l2[4] = {0.f, 0.f, 0.f, 0.f};
  f32x4 of[8] = {};
  int cur = 0;

  for (int t = 0; t <= qt; ++t) {
#pragma unroll
    for (int i = 0; i < 4; ++i)
      gload_lds16(vp[i], (char*)Vt + (i * 4 + w) * 1024);
#pragma unroll
    for (int i = 0; i < 4; ++i) vp[i] += 128;
    __builtin_amdgcn_sched_barrier(0);
    if (t < qt) {
      char* kd = (char*)&Ks[cur ^ 1][0];
#pragma unroll
      for (int i = 0; i < 6; ++i)
        gload_lds16(kp[i], kd + (i * 4 + w) * 1024);
#pragma unroll
      for (int i = 0; i < 6; ++i) kp[i] += kstr[i];
    }
    __builtin_amdgcn_sched_barrier(0);

    const char* KsL = (const char*)&Ks[cur][0];
    f32x4 sf[4] = {};
    __builtin_amdgcn_s_setprio(1);
#pragma unroll
    for (int j = 0; j < 4; ++j) {
#pragma unroll
      for (int ks = 0; ks < 6; ++ks) {
        int row = j * 16 + lc;
        bf16x8 kf = *(const bf16x8*)(KsL + row * 384 + (((ks * 4 + (lane >> 4)) ^ (row & 7)) << 4));
        sf[j] = __builtin_amdgcn_mfma_f32_16x16x32_bf16(qf[ks], kf, sf[j], 0, 0, 0);
      }
    }
    __builtin_amdgcn_s_setprio(0);

    float rm[4], fpr[4], ps[4];
#pragma unroll
    for (int j = 0; j < 4; ++j)
#pragma unroll
      for (int r = 0; r < 4; ++r) {
        float x_ = sf[j][r] * sc2;
        if (t == qt) {
          int colg = t * 64 + j * 16 + lc;
          int rowg = qt * 64 + w * 16 + lr + r;
          if (colg > rowg) x_ = -1e30f;
        }
        sf[j][r] = x_;
      }
#pragma unroll
    for (int r = 0; r < 4; ++r)
      rm[r] = fmaxf(fmaxf(sf[0][r], sf[1][r]), fmaxf(sf[2][r], sf[3][r]));
#pragma unroll
    for (int msk = 1; msk < 16; msk <<= 1)
#pragma unroll
      for (int r = 0; r < 4; ++r) rm[r] = fmaxf(rm[r], __shfl_xor(rm[r], msk));
#pragma unroll
    for (int r = 0; r < 4; ++r) {
      float mn = fmaxf(m2[r], rm[r]);
      fpr[r] = exp2f(m2[r] - mn);
      m2[r] = mn;
      ps[r] = 0.f;
    }
#pragma unroll
    for (int j = 0; j < 4; ++j)
#pragma unroll
      for (int r = 0; r < 4; ++r) {
        float p = exp2f(sf[j][r] - m2[r]);
        ps[r] += p;
        Ps[(w * 16 + lr + r) * 72 + j * 16 + lc] = f2bf(p);
      }
#pragma unroll
    for (int msk = 1; msk < 16; msk <<= 1)
#pragma unroll
      for (int r = 0; r < 4; ++r) ps[r] += __shfl_xor(ps[r], msk);
#pragma unroll
    for (int r = 0; r < 4; ++r) l2[r] = l2[r] * fpr[r] + ps[r];
#pragma unroll
    for (int nb = 0; nb < 8; ++nb)
#pragma unroll
      for (int r = 0; r < 4; ++r) of[nb][r] *= fpr[r];

    if (t < qt) { asm volatile("s_waitcnt vmcnt(6)" ::: "memory"); }
    else        { asm volatile("s_waitcnt vmcnt(0)" ::: "memory"); }
    asm volatile("s_waitcnt lgkmcnt(0)" ::: "memory");
    __builtin_amdgcn_s_barrier();
    __builtin_amdgcn_sched_barrier(0);

    __builtin_amdgcn_s_setprio(1);
#pragma unroll
    for (int ks = 0; ks < 2; ++ks) {
      bf16x8 ap = *(const bf16x8*)&Ps[(w * 16 + lc) * 72 + ks * 32 + ka];
#pragma unroll
      for (int nb = 0; nb < 8; ++nb) {
        int d = nb * 16 + lc;
        bf16x8 bvv = *(const bf16x8*)((const char*)Vt + d * 128 + (((ks * 4 + (lane >> 4)) ^ (d & 7)) << 4));
        of[nb] = __builtin_amdgcn_mfma_f32_16x16x32_bf16(ap, bvv, of[nb], 0, 0, 0);
      }
    }
    __builtin_amdgcn_s_setprio(0);

    asm volatile("s_waitcnt vmcnt(0)" ::: "memory");
    __builtin_amdgcn_s_barrier();
    __builtin_amdgcn_sched_barrier(0);
    cur ^= 1;
  }

#pragma unroll
  for (int r = 0; r < 4; ++r) {
    float inv = 1.f / l2[r];
    size_t m = (size_t)(bh >> 4) * 2048 + (size_t)qt * 64 + w * 16 + lr + r;
#pragma unroll
    for (int nb = 0; nb < 8; ++nb)
      o[m * 2048 + (bh & 15) * 128 + nb * 16 + lc] = f2bf(of[nb][r] * inv);
  }
}

// ---------------- launch ----------------------------------------------------
extern "C" void kernel_launch(void* const* d_in, const int* in_sizes, int n_in,
                              void* d_out, int out_size, void* d_ws, size_t ws_size,
                              hipStream_t stream) {
  const float* x = (const float*)d_in[0];
  const float* ln1w = (const float*)d_in[1];
  const float* ln1b = (const float*)d_in[2];
  const float* ln2w = (const float*)d_in[3];
  const float* ln2b = (const float*)d_in[4];
  const float* wq = (const float*)d_in[5];
  const float* bq = (const float*)d_in[6];
  const float* wdkv = (const float*)d_in[7];
  const float* bdkv = (const float*)d_in[8];
  const float* wkv = (const float*)d_in[9];
  const float* bkv = (const float*)d_in[10];
  const float* wo = (const float*)d_in[11];
  const float* bo = (const float*)d_in[12];
  const float* w1 = (const float*)d_in[13];
  const float* b1 = (const float*)d_in[14];
  const float* w2 = (const float*)d_in[15];
  const float* b2 = (const float*)d_in[16];
  (void)in_sizes; (void)n_in; (void)out_size; (void)ws_size;

  char* ws = (char*)d_ws;
  size_t off = 0;
  auto alloc = [&](size_t bytes) { void* p = ws + off; off += (bytes + 255) & ~(size_t)255; return p; };

  u16* wqT = (u16*)alloc(3072ull * 2048 * 2);
  u16* wdkvT = (u16*)alloc(640ull * 2048 * 2);   // 576 real rows, padded to 640
  u16* wkvT = (u16*)alloc(4096ull * 512 * 2);
  u16* woT = (u16*)alloc(2048ull * 2048 * 2);
  u16* w1T = (u16*)alloc(8192ull * 2048 * 2);
  u16* w2T = (u16*)alloc(2048ull * 8192 * 2);
  u16* hbuf = (u16*)alloc(4096ull * 2048 * 2);   // LN1 out; reused for LN2 out
  float* cosT = (float*)alloc(2048ull * 32 * 4);
  float* sinT = (float*)alloc(2048ull * 32 * 4);
  u16* obuf = (u16*)alloc(4096ull * 2048 * 2);
  char* G0 = ws + off;                           // FFN g overlays the region below
  u16* qallb = (u16*)alloc(32ull * 2048 * 192 * 2);
  float* qrb = (float*)alloc(4096ull * 1024 * 4);
  u16* ckvb = (u16*)alloc(4096ull * 512 * 2);
  float* krb = (float*)alloc(4096ull * 64 * 4);
  u16* krb_bf = (u16*)alloc(4096ull * 64 * 2);
  u16* knb2h = (u16*)alloc(32ull * 2048 * 128 * 2);
  u16* vb = (u16*)alloc(4096ull * 2048 * 2);
  u16* vbT = (u16*)alloc(32ull * 128 * 2048 * 2);
  u16* gb = (u16*)G0;                            // 67.1MB <= region below (~98MB)

  float* xout = (float*)d_out;                   // [4096][2048]
  float* nkv = xout + 4096ull * 2048;            // [4096][576]

  dim3 blk(256);
  dim3 blk5(512);
  k_transpose_bf16<<<dim3(64, 96), blk, 0, stream>>>(wq, wqT, 2048, 3072);
  k_transpose_bf16<<<dim3(64, 18), blk, 0, stream>>>(wdkv, wdkvT, 2048, 576);
  k_transpose_bf16<<<dim3(16, 128), blk, 0, stream>>>(wkv, wkvT, 512, 4096);
  k_transpose_bf16<<<dim3(64, 64), blk, 0, stream>>>(wo, woT, 2048, 2048);
  k_transpose_bf16<<<dim3(64, 256), blk, 0, stream>>>(w1, w1T, 2048, 8192);
  k_transpose_bf16<<<dim3(256, 64), blk, 0, stream>>>(w2, w2T, 8192, 2048);
  k_rope_table<<<dim3(256), blk, 0, stream>>>(cosT, sinT);
  k_ln<<<dim3(4096), blk, 0, stream>>>(x, ln1w, ln1b, hbuf);
  // q: M=4096 N=3072 K=2048 -> 256^2 tiles: 12*16=192
  k_gemm4<EP_Q><<<dim3(192), blk5, 0, stream>>>(hbuf, wqT, bq, 2048, 12, 3072, qallb, qrb, nullptr);
  k_gemm<EP_DKV><<<dim3(5, 32), blk, 0, stream>>>(hbuf, wdkvT, bdkv, 2048, 576, ckvb, nkv, krb, nullptr);
  k_rope_q<<<dim3(8192), blk, 0, stream>>>(qrb, cosT, sinT, qallb);
  k_rope_k<<<dim3(512), blk, 0, stream>>>(krb, cosT, sinT, nkv, krb_bf);
  // kv: M=4096 N=4096 K=512 -> 16*16=256
  k_gemm4<EP_KV><<<dim3(256), blk5, 0, stream>>>(ckvb, wkvT, bkv, 512, 16, 4096, knb2h, vb, nullptr);
  k_transpose_v<<<dim3(64, 4, 32), blk, 0, stream>>>(vb, vbT);
  k_attn<<<dim3(1024), blk, 0, stream>>>(qallb, knb2h, krb_bf, vbT, obuf);
  // o: M=4096 N=2048 K=2048 -> gemm2 grid 8*32=256 (fills chip)
  k_gemm2<EP_RES><<<dim3(256), blk5, 0, stream>>>(obuf, woT, bo, 2048, 8, 2048, xout, nullptr, x);
  k_ln<<<dim3(4096), blk, 0, stream>>>(xout, ln2w, ln2b, hbuf);
  // w1: M=4096 N=8192 K=2048 -> 32*16=512
  k_gemm4<EP_GELU><<<dim3(512), blk5, 0, stream>>>(hbuf, w1T, b1, 2048, 32, 8192, gb, nullptr, nullptr);
  // w2: M=4096 N=2048 K=8192 -> gemm2 grid 8*32=256 (fills chip)
  k_gemm2<EP_RES><<<dim3(256), blk5, 0, stream>>>(gb, w2T, b2, 8192, 8, 2048, xout, nullptr, xout);
}

// Round 12
// 767.073 us; speedup vs baseline: 1.0077x; 1.0077x over previous
//
#include <hip/hip_runtime.h>
#include <hip/hip_bf16.h>

// MLA transformer block on MI355X. Round 12: k_gemm4 bank-conflict fix for
// 64B rows -- granule swizzle p = g ^ ((row>>1)&3) on BOTH stage-source and
// read side (LDS dest stays linear). Quarter-wave reads: 8 banks x 2 lanes
// = conflict-free. Ring-4 schedule unchanged.

typedef short bf16x8 __attribute__((ext_vector_type(8)));
typedef float f32x4 __attribute__((ext_vector_type(4)));
typedef unsigned short u16;

#define BM 128
#define BN 128
#define BK 32

__device__ __forceinline__ u16 f2bf(float f) {
  unsigned int u = __builtin_bit_cast(unsigned int, f);
  u += 0x7FFFu + ((u >> 16) & 1u);
  return (u16)(u >> 16);
}

__device__ __forceinline__ void gload_lds16(const void* g, void* l) {
  __builtin_amdgcn_global_load_lds(
      (const __attribute__((address_space(1))) unsigned int*)(uintptr_t)g,
      (__attribute__((address_space(3))) unsigned int*)(unsigned int)(uintptr_t)l,
      16, 0, 0);
}

// ---------------- transpose + f32->bf16 : out[N][K] = (bf16) in[K][N] ------
__global__ __launch_bounds__(256) void k_transpose_bf16(
    const float* __restrict__ in, u16* __restrict__ out, int K, int N) {
  __shared__ float tile[32][33];
  int k0 = blockIdx.x * 32, n0 = blockIdx.y * 32;
  int tx = threadIdx.x & 31, ty = threadIdx.x >> 5;
#pragma unroll
  for (int i = 0; i < 4; ++i) {
    int k = k0 + ty + i * 8, n = n0 + tx;
    tile[ty + i * 8][tx] = (k < K && n < N) ? in[(size_t)k * N + n] : 0.f;
  }
  __syncthreads();
#pragma unroll
  for (int i = 0; i < 4; ++i) {
    int n = n0 + ty + i * 8, k = k0 + tx;
    if (n < N && k < K) out[(size_t)n * K + k] = f2bf(tile[tx][ty + i * 8]);
  }
}

// ---------------- V transpose per (b,h): vb[m][h*128+d] -> vbT[bh][d][s] ----
__global__ __launch_bounds__(256) void k_transpose_v(
    const u16* __restrict__ vb, u16* __restrict__ vbT) {
  __shared__ u16 tile[32][34];
  int bh = blockIdx.z, b = bh >> 4, h = bh & 15;
  int s0 = blockIdx.x * 32, d0 = blockIdx.y * 32;
  int tx = threadIdx.x & 31, ty = threadIdx.x >> 5;
#pragma unroll
  for (int i = 0; i < 4; ++i)
    tile[ty + i * 8][tx] =
        vb[((size_t)b * 2048 + s0 + ty + i * 8) * 2048 + h * 128 + d0 + tx];
  __syncthreads();
#pragma unroll
  for (int i = 0; i < 4; ++i)
    vbT[((size_t)bh * 128 + d0 + ty + i * 8) * 2048 + s0 + tx] = tile[tx][ty + i * 8];
}

// ---------------- RoPE tables: cos/sin[s][i], i<32 -------------------------
__global__ void k_rope_table(float* __restrict__ cosT, float* __restrict__ sinT) {
  int idx = blockIdx.x * 256 + threadIdx.x;
  if (idx >= 2048 * 32) return;
  int s = idx >> 5, i = idx & 31;
  float inv = exp2f(-(float)i * 0.41524101186092037f); // log2(10000)/32
  float a = (float)s * inv;
  cosT[idx] = cosf(a);
  sinT[idx] = sinf(a);
}

// ---------------- LayerNorm row=2048, out bf16 -----------------------------
__global__ __launch_bounds__(256) void k_ln(const float* __restrict__ x,
                                            const float* __restrict__ w,
                                            const float* __restrict__ b,
                                            u16* __restrict__ out) {
  const int row = blockIdx.x, tid = threadIdx.x;
  const float* xr = x + (size_t)row * 2048;
  float xv[8];
  *(float4*)&xv[0] = ((const float4*)xr)[tid * 2];
  *(float4*)&xv[4] = ((const float4*)xr)[tid * 2 + 1];
  float s = 0.f, ss = 0.f;
#pragma unroll
  for (int j = 0; j < 8; ++j) { s += xv[j]; ss += xv[j] * xv[j]; }
#pragma unroll
  for (int m_ = 32; m_; m_ >>= 1) { s += __shfl_xor(s, m_); ss += __shfl_xor(ss, m_); }
  __shared__ float red[8];
  const int wv = tid >> 6;
  if ((tid & 63) == 0) { red[wv] = s; red[wv + 4] = ss; }
  __syncthreads();
  s = red[0] + red[1] + red[2] + red[3];
  ss = red[4] + red[5] + red[6] + red[7];
  const float mean = s * (1.f / 2048.f);
  const float rs = rsqrtf(ss * (1.f / 2048.f) - mean * mean + 1e-5f);
  float wv8[8], bv8[8];
  *(float4*)&wv8[0] = ((const float4*)w)[tid * 2];
  *(float4*)&wv8[4] = ((const float4*)w)[tid * 2 + 1];
  *(float4*)&bv8[0] = ((const float4*)b)[tid * 2];
  *(float4*)&bv8[4] = ((const float4*)b)[tid * 2 + 1];
  u16 t[8] __attribute__((aligned(16)));
#pragma unroll
  for (int j = 0; j < 8; ++j) t[j] = f2bf((xv[j] - mean) * rs * wv8[j] + bv8[j]);
  *(int4*)&out[(size_t)row * 2048 + tid * 8] = *(int4*)t;
}

// ---------------- RoPE: qr f32 -> qall bf16 (cols 128..191) ----------------
__global__ void k_rope_q(const float* __restrict__ qr, const float* __restrict__ cosT,
                         const float* __restrict__ sinT, u16* __restrict__ qall) {
  int idx = blockIdx.x * 256 + threadIdx.x; // 4096*16*32
  if (idx >= 4096 * 16 * 32) return;
  int i = idx & 31, rest = idx >> 5;
  int h = rest & 15, m = rest >> 4;
  int s = m & 2047, b = m >> 11;
  float c = cosT[s * 32 + i], sn = sinT[s * 32 + i];
  const float* p = qr + (size_t)m * 1024 + h * 64 + i;
  float x0 = p[0], x1 = p[32];
  u16* q = qall + ((size_t)(b * 16 + h) * 2048 + s) * 192 + 128 + i;
  q[0] = f2bf(x0 * c - x1 * sn);
  q[32] = f2bf(x1 * c + x0 * sn);
}

// ---------------- RoPE: kr f32 -> krb_bf bf16 + nkv f32 --------------------
__global__ void k_rope_k(const float* __restrict__ kr, const float* __restrict__ cosT,
                         const float* __restrict__ sinT, float* __restrict__ nkv,
                         u16* __restrict__ krb_bf) {
  int idx = blockIdx.x * 256 + threadIdx.x; // 4096*32
  if (idx >= 4096 * 32) return;
  int i = idx & 31, m = idx >> 5;
  int s = m & 2047;
  float c = cosT[s * 32 + i], sn = sinT[s * 32 + i];
  const float* p = kr + (size_t)m * 64 + i;
  float x0 = p[0], x1 = p[32];
  float y0 = x0 * c - x1 * sn;
  float y1 = x1 * c + x0 * sn;
  nkv[(size_t)m * 576 + 512 + i] = y0;
  nkv[(size_t)m * 576 + 544 + i] = y1;
  krb_bf[(size_t)m * 64 + i] = f2bf(y0);
  krb_bf[(size_t)m * 64 + 32 + i] = f2bf(y1);
}

enum { EP_Q = 0, EP_DKV = 1, EP_KV = 2, EP_RES = 3, EP_GELU = 4 };

// ---------------- small GEMM (dkv only): m97 128x128xBK32 ------------------
template <int EP>
__global__ __launch_bounds__(256) void k_gemm(
    const u16* __restrict__ A, const u16* __restrict__ Bt,
    const float* __restrict__ bias, int K, int Nreal,
    void* out0_, void* out1_, void* out2_, const float* __restrict__ res) {
  __shared__ u16 As[BM * BK];
  __shared__ u16 Bs[BN * BK];
  const int tid = threadIdx.x;
  const int w = tid >> 6, lane = tid & 63;
  const int bm = blockIdx.y * BM, bn = blockIdx.x * BN;
  const int wr = (w >> 1) * 64, wc = (w & 1) * 64;

  const u16* Ag = A + (size_t)(bm + w * 32 + (lane >> 2)) * K + (lane & 3) * 8;
  const u16* Bg = Bt + (size_t)(bn + w * 32 + (lane >> 2)) * K + (lane & 3) * 8;
  char* lA = (char*)As + w * 2048;
  char* lB = (char*)Bs + w * 2048;

  f32x4 acc[4][4] = {};
  for (int k0 = 0; k0 < K; k0 += BK) {
    __syncthreads();
    gload_lds16(Ag, lA);
    gload_lds16(Ag + 16 * K, lA + 1024);
    gload_lds16(Bg, lB);
    gload_lds16(Bg + 16 * K, lB + 1024);
    Ag += BK; Bg += BK;
    __syncthreads();
    const int ka = (lane >> 4) * 8;
    const int lc = lane & 15;
    bf16x8 av[4], bv[4];
#pragma unroll
    for (int i = 0; i < 4; ++i) av[i] = *(const bf16x8*)&As[(wr + i * 16 + lc) * BK + ka];
#pragma unroll
    for (int j = 0; j < 4; ++j) bv[j] = *(const bf16x8*)&Bs[(wc + j * 16 + lc) * BK + ka];
#pragma unroll
    for (int i = 0; i < 4; ++i)
#pragma unroll
      for (int j = 0; j < 4; ++j)
        acc[i][j] = __builtin_amdgcn_mfma_f32_16x16x32_bf16(av[i], bv[j], acc[i][j], 0, 0, 0);
  }

  const int lr = (lane >> 4) * 4, lc = lane & 15;
#pragma unroll
  for (int i = 0; i < 4; ++i) {
#pragma unroll
    for (int j = 0; j < 4; ++j) {
      int col = bn + wc + j * 16 + lc;
      if (col >= Nreal) continue;
      float bb = bias ? bias[col] : 0.f;
#pragma unroll
      for (int r = 0; r < 4; ++r) {
        int row = bm + wr + i * 16 + lr + r;
        float c = acc[i][j][r] + bb;
        if constexpr (EP == EP_DKV) {
          u16* ckv = (u16*)out0_; float* nkv = (float*)out1_; float* kr = (float*)out2_;
          if (col < 512) { ckv[(size_t)row * 512 + col] = f2bf(c); nkv[(size_t)row * 576 + col] = c; }
          else kr[(size_t)row * 64 + (col - 512)] = c;
        }
      }
    }
  }
}

// ---------------- big GEMM v2: 128x256, BK=64, counted vmcnt (o, w2) -------
template <int EP>
__global__ __launch_bounds__(512, 2) void k_gemm2(
    const u16* __restrict__ A, const u16* __restrict__ Bt,
    const float* __restrict__ bias, int K, int gx, int Nreal,
    void* out0_, void* out1_, const float* __restrict__ res) {
  __shared__ u16 As[2][128 * 64];
  __shared__ u16 Bs[2][256 * 64];
  const int tid = threadIdx.x;
  const int w = tid >> 6, lane = tid & 63;
  const int q8 = (int)gridDim.x >> 3;
  const int u = ((int)blockIdx.x & 7) * q8 + ((int)blockIdx.x >> 3);
  const int bn = (u % gx) * 256, bm = (u / gx) * 128;
  const int wr = (w >> 2) * 64, wc = (w & 3) * 64;
  const int lc = lane & 15, hi = lane >> 4;

  const int rowid = tid >> 3;
  const int gsw = (tid & 7) ^ (rowid & 7);
  const u16* Ag = A + (size_t)(bm + rowid) * K + gsw * 8;
  const u16* Bg = Bt + (size_t)(bn + rowid) * K + gsw * 8;

  auto stage = [&](int buf, int k0) {
    char* lA = (char*)&As[buf][0] + tid * 16;
    char* lB = (char*)&Bs[buf][0] + tid * 16;
#pragma unroll
    for (int i = 0; i < 2; ++i)
      gload_lds16(Ag + (size_t)i * 64 * K + k0, lA + i * 8192);
#pragma unroll
    for (int i = 0; i < 4; ++i)
      gload_lds16(Bg + (size_t)i * 64 * K + k0, lB + i * 8192);
  };

  f32x4 acc[4][4] = {};
  const int NT = K >> 6;
  stage(0, 0);
  for (int t = 0; t < NT; ++t) {
    if (t + 1 < NT) {
      stage((t + 1) & 1, (t + 1) * 64);
      asm volatile("s_waitcnt vmcnt(6)" ::: "memory");
    } else {
      asm volatile("s_waitcnt vmcnt(0)" ::: "memory");
    }
    __builtin_amdgcn_s_barrier();
    __builtin_amdgcn_sched_barrier(0);
    const char* AsB = (const char*)&As[t & 1][0];
    const char* BsB = (const char*)&Bs[t & 1][0];
#pragma unroll
    for (int ks = 0; ks < 2; ++ks) {
      bf16x8 av[4], bv[4];
#pragma unroll
      for (int mi = 0; mi < 4; ++mi) {
        int row = wr + mi * 16 + lc;
        av[mi] = *(const bf16x8*)(AsB + row * 128 + (((ks * 4 + hi) ^ (row & 7)) << 4));
      }
#pragma unroll
      for (int ni = 0; ni < 4; ++ni) {
        int row = wc + ni * 16 + lc;
        bv[ni] = *(const bf16x8*)(BsB + row * 128 + (((ks * 4 + hi) ^ (row & 7)) << 4));
      }
#pragma unroll
      for (int mi = 0; mi < 4; ++mi)
#pragma unroll
        for (int ni = 0; ni < 4; ++ni)
          acc[mi][ni] = __builtin_amdgcn_mfma_f32_16x16x32_bf16(av[mi], bv[ni], acc[mi][ni], 0, 0, 0);
    }
    asm volatile("s_waitcnt lgkmcnt(0)" ::: "memory");
    __builtin_amdgcn_s_barrier();
  }

#pragma unroll
  for (int mi = 0; mi < 4; ++mi) {
#pragma unroll
    for (int ni = 0; ni < 4; ++ni) {
      int col = bn + wc + ni * 16 + lc;
      float bb = bias[col];
#pragma unroll
      for (int r = 0; r < 4; ++r) {
        int row = bm + wr + mi * 16 + hi * 4 + r;
        int b = row >> 11, s = row & 2047;
        float c = acc[mi][ni][r] + bb;
        if constexpr (EP == EP_Q) {
          u16* qall = (u16*)out0_; float* qr = (float*)out1_;
          int hh = col / 192, d = col - hh * 192;
          if (d < 128) qall[((size_t)(b * 16 + hh) * 2048 + s) * 192 + d] = f2bf(c);
          else qr[(size_t)row * 1024 + hh * 64 + (d - 128)] = c;
        } else if constexpr (EP == EP_KV) {
          u16* knb2h = (u16*)out0_; u16* vv = (u16*)out1_;
          int hh = col >> 8, d = col & 255;
          if (d < 128) knb2h[((size_t)(b * 16 + hh) * 2048 + s) * 128 + d] = f2bf(c);
          else vv[(size_t)row * 2048 + hh * 128 + (d - 128)] = f2bf(c);
        } else if constexpr (EP == EP_RES) {
          float* out = (float*)out0_;
          out[(size_t)row * Nreal + col] = res[(size_t)row * Nreal + col] + c;
        } else { // EP_GELU
          u16* g = (u16*)out0_;
          float gl = 0.5f * c * (1.f + erff(c * 0.70710678118f));
          g[(size_t)row * Nreal + col] = f2bf(gl);
        }
      }
    }
  }
}

// ---------------- big GEMM v4: 256x256, BK=32, 4-deep ring, swizzled -------
// Granule swizzle for 64B rows: physical granule p = g ^ ((row>>1)&3).
// Stage: LDS slot (row, p) sources global granule g = p ^ ((row>>1)&3).
// Read: logical granule hi lives at p = hi ^ ((row>>1)&3).
// Quarter-wave banks: (parity(row), p) -> 8 banks x 2 lanes = conflict-free.
template <int EP>
__global__ __launch_bounds__(512, 1) void k_gemm4(
    const u16* __restrict__ A, const u16* __restrict__ Bt,
    const float* __restrict__ bias, int K, int gx, int Nreal,
    void* out0_, void* out1_, const float* __restrict__ res) {
  __shared__ u16 As[4][256 * 32];
  __shared__ u16 Bs[4][256 * 32];
  const int tid = threadIdx.x;
  const int w = tid >> 6, lane = tid & 63;
  const int q8 = (int)gridDim.x >> 3;
  const int u = ((int)blockIdx.x & 7) * q8 + ((int)blockIdx.x >> 3);
  const int bn = (u % gx) * 256, bm = (u / gx) * 256;
  const int wm = (w >> 2) * 128, wn = (w & 3) * 64;
  const int lc = lane & 15, hi = lane >> 4;

  const u16* Agb = A + (size_t)bm * K;
  const u16* Bgb = Bt + (size_t)bn * K;
  // per-lane global source offsets (swizzled) for the 2 blocks this wave stages
  size_t srcoff[2];
#pragma unroll
  for (int i = 0; i < 2; ++i) {
    int G = (w * 2 + i) * 64 + lane;     // LDS granule 0..1023
    int row = G >> 2, p = G & 3;
    int g = p ^ ((row >> 1) & 3);        // global granule held by slot p
    srcoff[i] = (size_t)row * K + g * 8;
  }

  auto stage = [&](int buf, int k0) {
#pragma unroll
    for (int i = 0; i < 2; ++i) {
      gload_lds16(Agb + srcoff[i] + k0, (char*)&As[buf][0] + (w * 2 + i) * 1024);
      gload_lds16(Bgb + srcoff[i] + k0, (char*)&Bs[buf][0] + (w * 2 + i) * 1024);
    }
  };

  f32x4 acc[8][4] = {};
  const int NS = K >> 5;
  stage(0, 0);
  stage(1, 32);
  stage(2, 64);

  for (int s = 0; s < NS; ++s) {
    if (s + 2 < NS)      { asm volatile("s_waitcnt vmcnt(8)" ::: "memory"); }
    else if (s + 1 < NS) { asm volatile("s_waitcnt vmcnt(4)" ::: "memory"); }
    else                 { asm volatile("s_waitcnt vmcnt(0)" ::: "memory"); }
    __builtin_amdgcn_s_barrier();     // tile s visible; step s-1 reads done
    __builtin_amdgcn_sched_barrier(0);
    if (s + 3 < NS) stage((s + 3) & 3, (s + 3) * 32);
    __builtin_amdgcn_sched_barrier(0);

    const char* AsB = (const char*)&As[s & 3][0];
    const char* BsB = (const char*)&Bs[s & 3][0];
    bf16x8 av[8], bv[4];
#pragma unroll
    for (int mi = 0; mi < 8; ++mi) {
      int row = wm + mi * 16 + lc;
      av[mi] = *(const bf16x8*)(AsB + row * 64 + ((hi ^ ((row >> 1) & 3)) << 4));
    }
#pragma unroll
    for (int ni = 0; ni < 4; ++ni) {
      int row = wn + ni * 16 + lc;
      bv[ni] = *(const bf16x8*)(BsB + row * 64 + ((hi ^ ((row >> 1) & 3)) << 4));
    }
    asm volatile("s_waitcnt lgkmcnt(0)" ::: "memory");
    __builtin_amdgcn_sched_barrier(0);
    __builtin_amdgcn_s_setprio(1);
#pragma unroll
    for (int mi = 0; mi < 8; ++mi)
#pragma unroll
      for (int ni = 0; ni < 4; ++ni)
        acc[mi][ni] = __builtin_amdgcn_mfma_f32_16x16x32_bf16(av[mi], bv[ni], acc[mi][ni], 0, 0, 0);
    __builtin_amdgcn_s_setprio(0);
  }

#pragma unroll
  for (int mi = 0; mi < 8; ++mi) {
#pragma unroll
    for (int ni = 0; ni < 4; ++ni) {
      int col = bn + wn + ni * 16 + lc;
      float bb = bias[col];
#pragma unroll
      for (int r = 0; r < 4; ++r) {
        int row = bm + wm + mi * 16 + hi * 4 + r;
        int b = row >> 11, s = row & 2047;
        float c = acc[mi][ni][r] + bb;
        if constexpr (EP == EP_Q) {
          u16* qall = (u16*)out0_; float* qr = (float*)out1_;
          int hh = col / 192, d = col - hh * 192;
          if (d < 128) qall[((size_t)(b * 16 + hh) * 2048 + s) * 192 + d] = f2bf(c);
          else qr[(size_t)row * 1024 + hh * 64 + (d - 128)] = c;
        } else if constexpr (EP == EP_KV) {
          u16* knb2h = (u16*)out0_; u16* vv = (u16*)out1_;
          int hh = col >> 8, d = col & 255;
          if (d < 128) knb2h[((size_t)(b * 16 + hh) * 2048 + s) * 128 + d] = f2bf(c);
          else vv[(size_t)row * 2048 + hh * 128 + (d - 128)] = f2bf(c);
        } else if constexpr (EP == EP_RES) {
          float* out = (float*)out0_;
          out[(size_t)row * Nreal + col] = res[(size_t)row * Nreal + col] + c;
        } else { // EP_GELU
          u16* g = (u16*)out0_;
          float gl = 0.5f * c * (1.f + erff(c * 0.70710678118f));
          g[(size_t)row * Nreal + col] = f2bf(gl);
        }
      }
    }
  }
}

// ---------------- Flash attention: gload_lds staging, K dbuf, V single -----
__global__ __launch_bounds__(256) void k_attn(
    const u16* __restrict__ qall, const u16* __restrict__ knb2h,
    const u16* __restrict__ krb_bf, const u16* __restrict__ vbT,
    u16* __restrict__ o) {
  __shared__ u16 Ks[2][64 * 192];
  __shared__ u16 Vt[128 * 64];
  __shared__ u16 Ps[64 * 72];
  const int lin = blockIdx.x;
  const int qt = 31 - (lin >> 5);
  const int bh = (((lin >> 3) & 3) << 3) | (lin & 7);
  const int b = bh >> 4;
  const int tid = threadIdx.x, w = tid >> 6, lane = tid & 63;
  const float sc2 = 0.07216878365f * 1.4426950408f;
  const int lr = (lane >> 4) * 4, lc = lane & 15, ka = (lane >> 4) * 8;

  bf16x8 qf[6];
  {
    const u16* qrow = qall + ((size_t)bh * 2048 + qt * 64 + w * 16 + lc) * 192;
#pragma unroll
    for (int ks = 0; ks < 6; ++ks) qf[ks] = *(const bf16x8*)&qrow[ks * 32 + ka];
  }

  const char* kp[6];
  int kstr[6];
  {
    const char* knB = (const char*)(knb2h + (size_t)bh * 2048 * 128);
    const char* krB = (const char*)(krb_bf + (size_t)b * 2048 * 64);
#pragma unroll
    for (int i = 0; i < 6; ++i) {
      int G = (i * 4 + w) * 64 + lane;
      int row = G / 24, g = G - row * 24;
      int gs = g ^ (row & 7);
      if (gs < 16) { kp[i] = knB + row * 256 + gs * 16; kstr[i] = 16384; }
      else         { kp[i] = krB + row * 128 + (gs - 16) * 16; kstr[i] = 8192; }
    }
  }
  const char* vp[4];
  {
    const char* vB = (const char*)(vbT + (size_t)bh * 128 * 2048);
#pragma unroll
    for (int i = 0; i < 4; ++i) {
      int G = (i * 4 + w) * 64 + lane;
      int d = G >> 3, g = G & 7;
      vp[i] = vB + d * 4096 + ((g ^ (d & 7)) << 4);
    }
  }

#pragma unroll
  for (int i = 0; i < 6; ++i)
    gload_lds16(kp[i], (char*)&Ks[0][0] + (i * 4 + w) * 1024);
#pragma unroll
  for (int i = 0; i < 6; ++i) kp[i] += kstr[i];
  asm volatile("s_waitcnt vmcnt(0)" ::: "memory");
  __builtin_amdgcn_s_barrier();
  __builtin_amdgcn_sched_barrier(0);

  float m2[4] = {-1e30f, -1e30f, -1e30f, -1e30f};
  float l2[4] = {0.f, 0.f, 0.f, 0.f};
  f32x4 of[8] = {};
  int cur = 0;

  for (int t = 0; t <= qt; ++t) {
#pragma unroll
    for (int i = 0; i < 4; ++i)
      gload_lds16(vp[i], (char*)Vt + (i * 4 + w) * 1024);
#pragma unroll
    for (int i = 0; i < 4; ++i) vp[i] += 128;
    __builtin_amdgcn_sched_barrier(0);
    if (t < qt) {
      char* kd = (char*)&Ks[cur ^ 1][0];
#pragma unroll
      for (int i = 0; i < 6; ++i)
        gload_lds16(kp[i], kd + (i * 4 + w) * 1024);
#pragma unroll
      for (int i = 0; i < 6; ++i) kp[i] += kstr[i];
    }
    __builtin_amdgcn_sched_barrier(0);

    const char* KsL = (const char*)&Ks[cur][0];
    f32x4 sf[4] = {};
    __builtin_amdgcn_s_setprio(1);
#pragma unroll
    for (int j = 0; j < 4; ++j) {
#pragma unroll
      for (int ks = 0; ks < 6; ++ks) {
        int row = j * 16 + lc;
        bf16x8 kf = *(const bf16x8*)(KsL + row * 384 + (((ks * 4 + (lane >> 4)) ^ (row & 7)) << 4));
        sf[j] = __builtin_amdgcn_mfma_f32_16x16x32_bf16(qf[ks], kf, sf[j], 0, 0, 0);
      }
    }
    __builtin_amdgcn_s_setprio(0);

    float rm[4], fpr[4], ps[4];
#pragma unroll
    for (int j = 0; j < 4; ++j)
#pragma unroll
      for (int r = 0; r < 4; ++r) {
        float x_ = sf[j][r] * sc2;
        if (t == qt) {
          int colg = t * 64 + j * 16 + lc;
          int rowg = qt * 64 + w * 16 + lr + r;
          if (colg > rowg) x_ = -1e30f;
        }
        sf[j][r] = x_;
      }
#pragma unroll
    for (int r = 0; r < 4; ++r)
      rm[r] = fmaxf(fmaxf(sf[0][r], sf[1][r]), fmaxf(sf[2][r], sf[3][r]));
#pragma unroll
    for (int msk = 1; msk < 16; msk <<= 1)
#pragma unroll
      for (int r = 0; r < 4; ++r) rm[r] = fmaxf(rm[r], __shfl_xor(rm[r], msk));
#pragma unroll
    for (int r = 0; r < 4; ++r) {
      float mn = fmaxf(m2[r], rm[r]);
      fpr[r] = exp2f(m2[r] - mn);
      m2[r] = mn;
      ps[r] = 0.f;
    }
#pragma unroll
    for (int j = 0; j < 4; ++j)
#pragma unroll
      for (int r = 0; r < 4; ++r) {
        float p = exp2f(sf[j][r] - m2[r]);
        ps[r] += p;
        Ps[(w * 16 + lr + r) * 72 + j * 16 + lc] = f2bf(p);
      }
#pragma unroll
    for (int msk = 1; msk < 16; msk <<= 1)
#pragma unroll
      for (int r = 0; r < 4; ++r) ps[r] += __shfl_xor(ps[r], msk);
#pragma unroll
    for (int r = 0; r < 4; ++r) l2[r] = l2[r] * fpr[r] + ps[r];
#pragma unroll
    for (int nb = 0; nb < 8; ++nb)
#pragma unroll
      for (int r = 0; r < 4; ++r) of[nb][r] *= fpr[r];

    if (t < qt) { asm volatile("s_waitcnt vmcnt(6)" ::: "memory"); }
    else        { asm volatile("s_waitcnt vmcnt(0)" ::: "memory"); }
    asm volatile("s_waitcnt lgkmcnt(0)" ::: "memory");
    __builtin_amdgcn_s_barrier();
    __builtin_amdgcn_sched_barrier(0);

    __builtin_amdgcn_s_setprio(1);
#pragma unroll
    for (int ks = 0; ks < 2; ++ks) {
      bf16x8 ap = *(const bf16x8*)&Ps[(w * 16 + lc) * 72 + ks * 32 + ka];
#pragma unroll
      for (int nb = 0; nb < 8; ++nb) {
        int d = nb * 16 + lc;
        bf16x8 bvv = *(const bf16x8*)((const char*)Vt + d * 128 + (((ks * 4 + (lane >> 4)) ^ (d & 7)) << 4));
        of[nb] = __builtin_amdgcn_mfma_f32_16x16x32_bf16(ap, bvv, of[nb], 0, 0, 0);
      }
    }
    __builtin_amdgcn_s_setprio(0);

    asm volatile("s_waitcnt vmcnt(0)" ::: "memory");
    __builtin_amdgcn_s_barrier();
    __builtin_amdgcn_sched_barrier(0);
    cur ^= 1;
  }

#pragma unroll
  for (int r = 0; r < 4; ++r) {
    float inv = 1.f / l2[r];
    size_t m = (size_t)(bh >> 4) * 2048 + (size_t)qt * 64 + w * 16 + lr + r;
#pragma unroll
    for (int nb = 0; nb < 8; ++nb)
      o[m * 2048 + (bh & 15) * 128 + nb * 16 + lc] = f2bf(of[nb][r] * inv);
  }
}

// ---------------- launch ----------------------------------------------------
extern "C" void kernel_launch(void* const* d_in, const int* in_sizes, int n_in,
                              void* d_out, int out_size, void* d_ws, size_t ws_size,
                              hipStream_t stream) {
  const float* x = (const float*)d_in[0];
  const float* ln1w = (const float*)d_in[1];
  const float* ln1b = (const float*)d_in[2];
  const float* ln2w = (const float*)d_in[3];
  const float* ln2b = (const float*)d_in[4];
  const float* wq = (const float*)d_in[5];
  const float* bq = (const float*)d_in[6];
  const float* wdkv = (const float*)d_in[7];
  const float* bdkv = (const float*)d_in[8];
  const float* wkv = (const float*)d_in[9];
  const float* bkv = (const float*)d_in[10];
  const float* wo = (const float*)d_in[11];
  const float* bo = (const float*)d_in[12];
  const float* w1 = (const float*)d_in[13];
  const float* b1 = (const float*)d_in[14];
  const float* w2 = (const float*)d_in[15];
  const float* b2 = (const float*)d_in[16];
  (void)in_sizes; (void)n_in; (void)out_size; (void)ws_size;

  char* ws = (char*)d_ws;
  size_t off = 0;
  auto alloc = [&](size_t bytes) { void* p = ws + off; off += (bytes + 255) & ~(size_t)255; return p; };

  u16* wqT = (u16*)alloc(3072ull * 2048 * 2);
  u16* wdkvT = (u16*)alloc(640ull * 2048 * 2);   // 576 real rows, padded to 640
  u16* wkvT = (u16*)alloc(4096ull * 512 * 2);
  u16* woT = (u16*)alloc(2048ull * 2048 * 2);
  u16* w1T = (u16*)alloc(8192ull * 2048 * 2);
  u16* w2T = (u16*)alloc(2048ull * 8192 * 2);
  u16* hbuf = (u16*)alloc(4096ull * 2048 * 2);   // LN1 out; reused for LN2 out
  float* cosT = (float*)alloc(2048ull * 32 * 4);
  float* sinT = (float*)alloc(2048ull * 32 * 4);
  u16* obuf = (u16*)alloc(4096ull * 2048 * 2);
  char* G0 = ws + off;                           // FFN g overlays the region below
  u16* qallb = (u16*)alloc(32ull * 2048 * 192 * 2);
  float* qrb = (float*)alloc(4096ull * 1024 * 4);
  u16* ckvb = (u16*)alloc(4096ull * 512 * 2);
  float* krb = (float*)alloc(4096ull * 64 * 4);
  u16* krb_bf = (u16*)alloc(4096ull * 64 * 2);
  u16* knb2h = (u16*)alloc(32ull * 2048 * 128 * 2);
  u16* vb = (u16*)alloc(4096ull * 2048 * 2);
  u16* vbT = (u16*)alloc(32ull * 128 * 2048 * 2);
  u16* gb = (u16*)G0;                            // 67.1MB <= region below (~98MB)

  float* xout = (float*)d_out;                   // [4096][2048]
  float* nkv = xout + 4096ull * 2048;            // [4096][576]

  dim3 blk(256);
  dim3 blk5(512);
  k_transpose_bf16<<<dim3(64, 96), blk, 0, stream>>>(wq, wqT, 2048, 3072);
  k_transpose_bf16<<<dim3(64, 18), blk, 0, stream>>>(wdkv, wdkvT, 2048, 576);
  k_transpose_bf16<<<dim3(16, 128), blk, 0, stream>>>(wkv, wkvT, 512, 4096);
  k_transpose_bf16<<<dim3(64, 64), blk, 0, stream>>>(wo, woT, 2048, 2048);
  k_transpose_bf16<<<dim3(64, 256), blk, 0, stream>>>(w1, w1T, 2048, 8192);
  k_transpose_bf16<<<dim3(256, 64), blk, 0, stream>>>(w2, w2T, 8192, 2048);
  k_rope_table<<<dim3(256), blk, 0, stream>>>(cosT, sinT);
  k_ln<<<dim3(4096), blk, 0, stream>>>(x, ln1w, ln1b, hbuf);
  // q: M=4096 N=3072 K=2048 -> 256^2 tiles: 12*16=192
  k_gemm4<EP_Q><<<dim3(192), blk5, 0, stream>>>(hbuf, wqT, bq, 2048, 12, 3072, qallb, qrb, nullptr);
  k_gemm<EP_DKV><<<dim3(5, 32), blk, 0, stream>>>(hbuf, wdkvT, bdkv, 2048, 576, ckvb, nkv, krb, nullptr);
  k_rope_q<<<dim3(8192), blk, 0, stream>>>(qrb, cosT, sinT, qallb);
  k_rope_k<<<dim3(512), blk, 0, stream>>>(krb, cosT, sinT, nkv, krb_bf);
  // kv: M=4096 N=4096 K=512 -> 16*16=256
  k_gemm4<EP_KV><<<dim3(256), blk5, 0, stream>>>(ckvb, wkvT, bkv, 512, 16, 4096, knb2h, vb, nullptr);
  k_transpose_v<<<dim3(64, 4, 32), blk, 0, stream>>>(vb, vbT);
  k_attn<<<dim3(1024), blk, 0, stream>>>(qallb, knb2h, krb_bf, vbT, obuf);
  // o: M=4096 N=2048 K=2048 -> gemm2 grid 8*32=256 (fills chip)
  k_gemm2<EP_RES><<<dim3(256), blk5, 0, stream>>>(obuf, woT, bo, 2048, 8, 2048, xout, nullptr, x);
  k_ln<<<dim3(4096), blk, 0, stream>>>(xout, ln2w, ln2b, hbuf);
  // w1: M=4096 N=8192 K=2048 -> 32*16=512
  k_gemm4<EP_GELU><<<dim3(512), blk5, 0, stream>>>(hbuf, w1T, b1, 2048, 32, 8192, gb, nullptr, nullptr);
  // w2: M=4096 N=2048 K=8192 -> gemm2 grid 8*32=256 (fills chip)
  k_gemm2<EP_RES><<<dim3(256), blk5, 0, stream>>>(gb, w2T, b2, 8192, 8, 2048, xout, nullptr, xout);
}